// Round 2
// 224.080 us; speedup vs baseline: 1.0292x; 1.0292x over previous
//
#include <hip/hip_runtime.h>
#include <math.h>

#define IN_F   256
#define OUT_F  128
#define HEADS  4
#define HD     (HEADS * OUT_F)   // 512
#define NEG    0.2f
#define CAP    64                // per-node in-edge capacity (mean deg 16; P(deg>64) ~ 1e-18)

typedef __attribute__((ext_vector_type(8))) short short8;   // 8 bf16 = 4 VGPRs
typedef __attribute__((ext_vector_type(4))) float f32x4;

typedef __attribute__((address_space(1))) const void* gp_t;
typedef __attribute__((address_space(3))) void* lp_t;

static __device__ __forceinline__ ushort f2bf(float f) {
    union { float f; unsigned u; } v; v.f = f;
    unsigned r = (v.u + 0x7FFFu + ((v.u >> 16) & 1u)) >> 16;   // RNE
    return (ushort)r;
}
static __device__ __forceinline__ float bflo(unsigned u) {
    union { unsigned u; float f; } v; v.u = u << 16; return v.f;
}
static __device__ __forceinline__ float bfhi(unsigned u) {
    union { unsigned u; float f; } v; v.u = u & 0xFFFF0000u; return v.f;
}

// ---------------- WT bf16 [512][256] + va = W @ att  (fp32 [4][256] x2) ----------------
__global__ __launch_bounds__(256) void cvt_wt(const float* __restrict__ W,
                                              ushort* __restrict__ WT) {
    int idx = blockIdx.x * blockDim.x + threadIdx.x;   // 512*256
    int n = idx >> 8, k = idx & 255;
    WT[idx] = f2bf(W[k * HD + n]);
}
__global__ __launch_bounds__(256) void calc_va(const float* __restrict__ W,
                                               const float* __restrict__ att_src,
                                               const float* __restrict__ att_dst,
                                               float* __restrict__ va_s,
                                               float* __restrict__ va_d) {
    int idx = blockIdx.x * blockDim.x + threadIdx.x;   // 4*256
    int h = idx >> 8, k = idx & 255;
    const float* wr = W + (size_t)k * HD + h * OUT_F;
    const float* as = att_src + h * OUT_F;
    const float* ad = att_dst + h * OUT_F;
    float ss = 0.f, sd = 0.f;
#pragma unroll 8
    for (int c = 0; c < OUT_F; ++c) {
        float w = wr[c];
        ss = fmaf(w, as[c], ss);
        sd = fmaf(w, ad[c], sd);
    }
    va_s[idx] = ss;
    va_d[idx] = sd;
}

// ------- fused: X f32 -> Xb bf16, plus a_s/a_d = x . va (wave per node) -------
__global__ __launch_bounds__(256) void fused_x(const float* __restrict__ X,
                                               const float* __restrict__ va_s,
                                               const float* __restrict__ va_d,
                                               ushort* __restrict__ Xb,
                                               float* __restrict__ a_s,
                                               float* __restrict__ a_d,
                                               int n_nodes) {
    const int lane = threadIdx.x & 63;
    const int node = blockIdx.x * 4 + (threadIdx.x >> 6);
    if (node >= n_nodes) return;
    float4 v = *(const float4*)(X + (size_t)node * IN_F + lane * 4);
    ushort4 o; o.x = f2bf(v.x); o.y = f2bf(v.y); o.z = f2bf(v.z); o.w = f2bf(v.w);
    *(ushort4*)(Xb + (size_t)node * IN_F + lane * 4) = o;

    float ps[HEADS], pd[HEADS];
#pragma unroll
    for (int hd = 0; hd < HEADS; ++hd) {
        float4 s4 = *(const float4*)(va_s + hd * IN_F + lane * 4);
        float4 d4 = *(const float4*)(va_d + hd * IN_F + lane * 4);
        ps[hd] = v.x * s4.x + v.y * s4.y + v.z * s4.z + v.w * s4.w;
        pd[hd] = v.x * d4.x + v.y * d4.y + v.z * d4.z + v.w * d4.w;
    }
#pragma unroll
    for (int off = 32; off > 0; off >>= 1) {
#pragma unroll
        for (int hd = 0; hd < HEADS; ++hd) {
            ps[hd] += __shfl_xor(ps[hd], off, 64);
            pd[hd] += __shfl_xor(pd[hd], off, 64);
        }
    }
    if (lane == 0) {
        float4 s4 = make_float4(ps[0], ps[1], ps[2], ps[3]);
        float4 d4 = make_float4(pd[0], pd[1], pd[2], pd[3]);
        *(float4*)(a_s + node * 4) = s4;
        *(float4*)(a_d + node * 4) = d4;
    }
}

// ---------------- Hb(bf16) = Xb @ WT^T via bf16 MFMA, global_load_lds staging ----------------
// LDS layout: unpadded 32-ushort rows, chunk slot s holds global chunk s ^ ((row>>1)&3).
// DMA writes lane*16B contiguous (required); fragment ds_read_b128 lands 2-way on banks (free).
#define GBM 128
#define GBN 128
#define GBK 32

__global__ __launch_bounds__(256) void gemm_mfma(const ushort* __restrict__ Xb,
                                                 const ushort* __restrict__ WT,
                                                 ushort* __restrict__ Hb,
                                                 int n_nodes) {
    __shared__ ushort As[GBM][GBK];
    __shared__ ushort Bs[GBN][GBK];
    const int tid = threadIdx.x;
    const int m0 = blockIdx.y * GBM;
    const int n0 = blockIdx.x * GBN;
    const int wave = tid >> 6, lane = tid & 63;
    const int wm = (wave & 1) * 64, wn = (wave >> 1) * 64;
    const int l15 = lane & 15, quad = lane >> 4;

    // staging: wave w covers rows w*16..w*16+15 (and +64); lane -> (row, slot)
    const int rr = lane >> 2;                       // row within strip
    const int cg = (lane & 3) ^ ((lane >> 3) & 3);  // swizzled global chunk
    const int rA = wave * 16 + rr;
    const ushort* gA0 = Xb + (size_t)(m0 + rA) * IN_F + cg * 8;
    const ushort* gA1 = Xb + (size_t)(m0 + 64 + rA) * IN_F + cg * 8;
    const ushort* gB0 = WT + (size_t)(n0 + rA) * IN_F + cg * 8;
    const ushort* gB1 = WT + (size_t)(n0 + 64 + rA) * IN_F + cg * 8;
    ushort* lA0 = &As[wave * 16][0];
    ushort* lA1 = &As[64 + wave * 16][0];
    ushort* lB0 = &Bs[wave * 16][0];
    ushort* lB1 = &Bs[64 + wave * 16][0];

    f32x4 acc[4][4];
#pragma unroll
    for (int i = 0; i < 4; ++i)
#pragma unroll
        for (int j = 0; j < 4; ++j) acc[i][j] = (f32x4){0.f, 0.f, 0.f, 0.f};

    const int ks = (quad ^ ((l15 >> 1) & 3)) * 8;   // swizzled fragment k-offset

    for (int k0 = 0; k0 < IN_F; k0 += GBK) {
        __syncthreads();
        __builtin_amdgcn_global_load_lds((gp_t)(gA0 + k0), (lp_t)lA0, 16, 0, 0);
        __builtin_amdgcn_global_load_lds((gp_t)(gA1 + k0), (lp_t)lA1, 16, 0, 0);
        __builtin_amdgcn_global_load_lds((gp_t)(gB0 + k0), (lp_t)lB0, 16, 0, 0);
        __builtin_amdgcn_global_load_lds((gp_t)(gB1 + k0), (lp_t)lB1, 16, 0, 0);
        __syncthreads();

        short8 af[4], bf_[4];
#pragma unroll
        for (int f = 0; f < 4; ++f) {
            af[f]  = *(const short8*)&As[wm + f * 16 + l15][ks];
            bf_[f] = *(const short8*)&Bs[wn + f * 16 + l15][ks];
        }
#pragma unroll
        for (int fm = 0; fm < 4; ++fm)
#pragma unroll
            for (int fn = 0; fn < 4; ++fn)
                acc[fm][fn] = __builtin_amdgcn_mfma_f32_16x16x32_bf16(
                    af[fm], bf_[fn], acc[fm][fn], 0, 0, 0);
    }

#pragma unroll
    for (int fm = 0; fm < 4; ++fm) {
        int gmb = m0 + wm + fm * 16 + quad * 4;
#pragma unroll
        for (int reg = 0; reg < 4; ++reg) {
            int gm = gmb + reg;
            if (gm < n_nodes) {
#pragma unroll
                for (int fn = 0; fn < 4; ++fn)
                    Hb[(size_t)gm * HD + n0 + wn + fn * 16 + l15] =
                        f2bf(acc[fm][fn][reg]);
            }
        }
    }
}

// --------- bucket edges by dst: table[d][r] = src ---------
__global__ __launch_bounds__(256) void build_table(const int* __restrict__ src,
                                                   const int* __restrict__ dst,
                                                   int* __restrict__ cursor,
                                                   int* __restrict__ table,
                                                   int n_edges) {
    int e = blockIdx.x * blockDim.x + threadIdx.x;
    if (e >= n_edges) return;
    int d = dst[e];
    int r = atomicAdd(&cursor[d], 1);
    if (r < CAP) table[(size_t)d * CAP + r] = src[e];
}

// --------- fused softmax + aggregation: wave per node ---------
// Phase 1 (lane = edge): butterfly softmax -> per-edge exp weights, published to
// per-wave LDS head-major (stride 68 so the 4 head groups hit distinct banks).
// Phase 2 (lane = head lane>>4, channels (lane&15)*8..+8): each source row is
// fetched with ONE dwordx4 per lane (1 KB/wave/instr), weights come back as
// ds_read_b128 broadcasts (1 LDS read per 4 edges replaces 16 shuffles).
#define ACCUM(U, WV)                                                   \
    acc[0] = fmaf((WV), bflo((U).x), acc[0]);                          \
    acc[1] = fmaf((WV), bfhi((U).x), acc[1]);                          \
    acc[2] = fmaf((WV), bflo((U).y), acc[2]);                          \
    acc[3] = fmaf((WV), bfhi((U).y), acc[3]);                          \
    acc[4] = fmaf((WV), bflo((U).z), acc[4]);                          \
    acc[5] = fmaf((WV), bfhi((U).z), acc[5]);                          \
    acc[6] = fmaf((WV), bflo((U).w), acc[6]);                          \
    acc[7] = fmaf((WV), bfhi((U).w), acc[7]);

__global__ __launch_bounds__(256) void gat_agg(const ushort* __restrict__ Hb,
                                               const float* __restrict__ a_s,
                                               const float* __restrict__ a_d,
                                               const int* __restrict__ cursor,
                                               const int* __restrict__ table,
                                               const float* __restrict__ bias,
                                               float* __restrict__ out,
                                               int n_nodes) {
    __shared__ float ws[4][4 * 68 + 4];         // [wave][head*68 + edge]
    const int lane = threadIdx.x & 63;
    const int wid  = threadIdx.x >> 6;
    int n = blockIdx.x * 4 + wid;
    const bool valid = n < n_nodes;
    if (!valid) n = n_nodes - 1;                // clamp: keep all waves for barrier
    int deg = cursor[n]; if (deg > CAP) deg = CAP;
    const int* row = table + (size_t)n * CAP;

    // ---- softmax over self + in-edges (lane e owns edge e) ----
    const float4 ad4 = *(const float4*)(a_d + n * 4);
    const float4 as4 = *(const float4*)(a_s + n * 4);
    const float ad[4] = {ad4.x, ad4.y, ad4.z, ad4.w};
    float aself[4];
    {
        const float asn[4] = {as4.x, as4.y, as4.z, as4.w};
#pragma unroll
        for (int hd = 0; hd < 4; ++hd) {
            float al0 = asn[hd] + ad[hd];
            aself[hd] = al0 > 0.f ? al0 : NEG * al0;
        }
    }
    const bool act = lane < deg;
    float al[4];
    {
        int s = act ? row[lane] : 0;
        float4 av = *(const float4*)(a_s + s * 4);
        const float as_[4] = {av.x, av.y, av.z, av.w};
#pragma unroll
        for (int hd = 0; hd < 4; ++hd) {
            float a = as_[hd] + ad[hd];
            a = a > 0.f ? a : NEG * a;
            al[hd] = act ? a : -1e30f;
        }
    }
    float m[4];
#pragma unroll
    for (int hd = 0; hd < 4; ++hd) m[hd] = al[hd];
#pragma unroll
    for (int off = 32; off > 0; off >>= 1)
#pragma unroll
        for (int hd = 0; hd < 4; ++hd)
            m[hd] = fmaxf(m[hd], __shfl_xor(m[hd], off, 64));
#pragma unroll
    for (int hd = 0; hd < 4; ++hd) m[hd] = fmaxf(m[hd], aself[hd]);

    float w[4], den[4];
#pragma unroll
    for (int hd = 0; hd < 4; ++hd) {
        w[hd] = act ? __expf(al[hd] - m[hd]) : 0.f;
        den[hd] = w[hd];
    }
#pragma unroll
    for (int off = 32; off > 0; off >>= 1)
#pragma unroll
        for (int hd = 0; hd < 4; ++hd)
            den[hd] += __shfl_xor(den[hd], off, 64);

    float es[4], rdv[4];
#pragma unroll
    for (int hd = 0; hd < 4; ++hd) {
        es[hd] = __expf(aself[hd] - m[hd]);
        rdv[hd] = 1.f / (den[hd] + es[hd]);
    }

    // publish per-edge weights head-major (w=0 for lanes >= deg)
#pragma unroll
    for (int hd = 0; hd < 4; ++hd) ws[wid][hd * 68 + lane] = w[hd];
    __syncthreads();

    // ---- aggregation: lane owns head lane>>4, float channels (lane&15)*8.. ----
    const int hsel = lane >> 4;
    const float rdv_h = hsel == 0 ? rdv[0] : hsel == 1 ? rdv[1]
                      : hsel == 2 ? rdv[2] : rdv[3];
    const float es_h  = hsel == 0 ? es[0]  : hsel == 1 ? es[1]
                      : hsel == 2 ? es[2]  : es[3];
    const float* wrow = &ws[wid][hsel * 68];
    const uint4* hb4 = (const uint4*)Hb;        // one node row = 64 uint4

    float acc[8];
    {
        uint4 u = hb4[(size_t)n * 64 + lane];
        acc[0] = es_h * bflo(u.x); acc[1] = es_h * bfhi(u.x);
        acc[2] = es_h * bflo(u.y); acc[3] = es_h * bfhi(u.y);
        acc[4] = es_h * bflo(u.z); acc[5] = es_h * bfhi(u.z);
        acc[6] = es_h * bflo(u.w); acc[7] = es_h * bfhi(u.w);
    }
    int e = 0;
    for (; e + 8 <= deg; e += 8) {
        int4 ra = *(const int4*)(row + e);
        int4 rb = *(const int4*)(row + e + 4);
        uint4 u0 = hb4[(size_t)ra.x * 64 + lane];
        uint4 u1 = hb4[(size_t)ra.y * 64 + lane];
        uint4 u2 = hb4[(size_t)ra.z * 64 + lane];
        uint4 u3 = hb4[(size_t)ra.w * 64 + lane];
        uint4 u4 = hb4[(size_t)rb.x * 64 + lane];
        uint4 u5 = hb4[(size_t)rb.y * 64 + lane];
        uint4 u6 = hb4[(size_t)rb.z * 64 + lane];
        uint4 u7 = hb4[(size_t)rb.w * 64 + lane];
        float4 wa = *(const float4*)(wrow + e);
        float4 wb = *(const float4*)(wrow + e + 4);
        ACCUM(u0, wa.x); ACCUM(u1, wa.y); ACCUM(u2, wa.z); ACCUM(u3, wa.w);
        ACCUM(u4, wb.x); ACCUM(u5, wb.y); ACCUM(u6, wb.z); ACCUM(u7, wb.w);
    }
    for (; e + 4 <= deg; e += 4) {
        int4 ra = *(const int4*)(row + e);
        uint4 u0 = hb4[(size_t)ra.x * 64 + lane];
        uint4 u1 = hb4[(size_t)ra.y * 64 + lane];
        uint4 u2 = hb4[(size_t)ra.z * 64 + lane];
        uint4 u3 = hb4[(size_t)ra.w * 64 + lane];
        float4 wa = *(const float4*)(wrow + e);
        ACCUM(u0, wa.x); ACCUM(u1, wa.y); ACCUM(u2, wa.z); ACCUM(u3, wa.w);
    }
    for (; e < deg; ++e) {
        uint4 u = hb4[(size_t)row[e] * 64 + lane];
        float wv = wrow[e];
        ACCUM(u, wv);
    }

    // ---- mean over heads: reduce across the four 16-lane groups ----
#pragma unroll
    for (int c = 0; c < 8; ++c) {
        float v = acc[c] * rdv_h;
        v += __shfl_xor(v, 16, 64);
        v += __shfl_xor(v, 32, 64);
        acc[c] = v;
    }
    if (valid && lane < 16) {
        float4 b0 = *(const float4*)(bias + lane * 8);
        float4 b1 = *(const float4*)(bias + lane * 8 + 4);
        float4 o0, o1;
        o0.x = tanhf(0.25f * acc[0] + b0.x);
        o0.y = tanhf(0.25f * acc[1] + b0.y);
        o0.z = tanhf(0.25f * acc[2] + b0.z);
        o0.w = tanhf(0.25f * acc[3] + b0.w);
        o1.x = tanhf(0.25f * acc[4] + b1.x);
        o1.y = tanhf(0.25f * acc[5] + b1.y);
        o1.z = tanhf(0.25f * acc[6] + b1.z);
        o1.w = tanhf(0.25f * acc[7] + b1.w);
        *(float4*)(out + (size_t)n * OUT_F + lane * 8) = o0;
        *(float4*)(out + (size_t)n * OUT_F + lane * 8 + 4) = o1;
    }
}

extern "C" void kernel_launch(void* const* d_in, const int* in_sizes, int n_in,
                              void* d_out, int out_size, void* d_ws, size_t ws_size,
                              hipStream_t stream) {
    const float* x       = (const float*)d_in[0];
    const int*   ei      = (const int*)d_in[1];
    const float* W       = (const float*)d_in[2];
    const float* att_src = (const float*)d_in[3];
    const float* att_dst = (const float*)d_in[4];
    const float* bias    = (const float*)d_in[5];
    float* out = (float*)d_out;

    const int n_nodes = in_sizes[0] / IN_F;     // 30000
    const int n_edges = in_sizes[1] / 2;        // 480000
    const int* src = ei;
    const int* dst = ei + n_edges;

    char* ws = (char*)d_ws;
    size_t off = 0;
    auto alloc = [&](size_t bytes) -> void* {
        void* p = ws + off;
        off = (off + bytes + 255) & ~(size_t)255;
        return p;
    };
    ushort* Xb     = (ushort*)alloc((size_t)n_nodes * IN_F * sizeof(ushort));   // 15.4 MB
    ushort* Hb     = (ushort*)alloc((size_t)n_nodes * HD * sizeof(ushort));     // 30.7 MB
    ushort* WT     = (ushort*)alloc((size_t)HD * IN_F * sizeof(ushort));        // 0.26 MB
    float*  va_s   = (float*)alloc((size_t)HEADS * IN_F * sizeof(float));
    float*  va_d   = (float*)alloc((size_t)HEADS * IN_F * sizeof(float));
    float*  a_s    = (float*)alloc((size_t)n_nodes * HEADS * sizeof(float));
    float*  a_d    = (float*)alloc((size_t)n_nodes * HEADS * sizeof(float));
    int*    cursor = (int*)alloc((size_t)n_nodes * sizeof(int));
    int*    table  = (int*)alloc((size_t)n_nodes * CAP * sizeof(int));          // 7.7 MB
    (void)ws_size; (void)n_in; (void)out_size;

    hipMemsetAsync(cursor, 0, (size_t)n_nodes * sizeof(int), stream);

    cvt_wt<<<(HD * IN_F) / 256, 256, 0, stream>>>(W, WT);
    calc_va<<<(HEADS * IN_F) / 256, 256, 0, stream>>>(W, att_src, att_dst, va_s, va_d);
    fused_x<<<(n_nodes + 3) / 4, 256, 0, stream>>>(x, va_s, va_d, Xb, a_s, a_d, n_nodes);
    build_table<<<(n_edges + 255) / 256, 256, 0, stream>>>(src, dst, cursor, table, n_edges);

    dim3 ggrid(HD / GBN, (n_nodes + GBM - 1) / GBM);   // 4 x 235
    gemm_mfma<<<ggrid, 256, 0, stream>>>(Xb, WT, Hb, n_nodes);

    gat_agg<<<(n_nodes + 3) / 4, 256, 0, stream>>>(Hb, a_s, a_d, cursor, table,
                                                   bias, out, n_nodes);
}

// Round 3
// 216.934 us; speedup vs baseline: 1.0631x; 1.0329x over previous
//
#include <hip/hip_runtime.h>
#include <math.h>

#define IN_F   256
#define OUT_F  128
#define HEADS  4
#define HD     (HEADS * OUT_F)   // 512
#define K2     1024              // stacked contraction: 4 heads x 256
#define NEG    0.2f
#define CAP    64                // per-node in-edge capacity (mean deg 16; P(deg>64) ~ 1e-18)

typedef __attribute__((ext_vector_type(8))) short short8;   // 8 bf16 = 4 VGPRs
typedef __attribute__((ext_vector_type(4))) float f32x4;

typedef __attribute__((address_space(1))) const void* gp_t;
typedef __attribute__((address_space(3))) void* lp_t;

static __device__ __forceinline__ ushort f2bf(float f) {
    union { float f; unsigned u; } v; v.f = f;
    unsigned r = (v.u + 0x7FFFu + ((v.u >> 16) & 1u)) >> 16;   // RNE
    return (ushort)r;
}
static __device__ __forceinline__ float bflo(unsigned u) {
    union { unsigned u; float f; } v; v.u = u << 16; return v.f;
}
static __device__ __forceinline__ float bfhi(unsigned u) {
    union { unsigned u; float f; } v; v.u = u & 0xFFFF0000u; return v.f;
}

// ---------------- WT2 bf16 [128][1024]: WT2[cout][h*256+c] = W[c][h*128+cout] ----------------
__global__ __launch_bounds__(256) void cvt_wt2(const float* __restrict__ W,
                                               ushort* __restrict__ WT2) {
    int idx = blockIdx.x * blockDim.x + threadIdx.x;   // 128*1024
    int cout = idx >> 10, kk = idx & 1023;
    int h = kk >> 8, c = kk & 255;
    WT2[idx] = f2bf(W[(size_t)c * HD + h * OUT_F + cout]);
}

// ---------------- va = W @ att  (wave per (h,k) pair; butterfly reduce) ----------------
__global__ __launch_bounds__(256) void calc_va(const float* __restrict__ W,
                                               const float* __restrict__ att_src,
                                               const float* __restrict__ att_dst,
                                               float* __restrict__ va_s,
                                               float* __restrict__ va_d) {
    const int lane = threadIdx.x & 63;
    const int p = blockIdx.x * 4 + (threadIdx.x >> 6);   // 0..1023 = h*256 + k
    const int h = p >> 8;
    const int k = p & 255;
    const float* wr = W + (size_t)k * HD + h * OUT_F;
    float w0 = wr[lane], w1 = wr[lane + 64];
    float s0 = att_src[h * OUT_F + lane], s1 = att_src[h * OUT_F + lane + 64];
    float d0 = att_dst[h * OUT_F + lane], d1 = att_dst[h * OUT_F + lane + 64];
    float ss = w0 * s0 + w1 * s1;
    float sd = w0 * d0 + w1 * d1;
#pragma unroll
    for (int off = 32; off > 0; off >>= 1) {
        ss += __shfl_xor(ss, off, 64);
        sd += __shfl_xor(sd, off, 64);
    }
    if (lane == 0) { va_s[p] = ss; va_d[p] = sd; }
}

// ------- fused: X f32 -> Xb bf16, plus a_s/a_d = x . va (wave per node) -------
__global__ __launch_bounds__(256) void fused_x(const float* __restrict__ X,
                                               const float* __restrict__ va_s,
                                               const float* __restrict__ va_d,
                                               ushort* __restrict__ Xb,
                                               float* __restrict__ a_s,
                                               float* __restrict__ a_d,
                                               int n_nodes) {
    const int lane = threadIdx.x & 63;
    const int node = blockIdx.x * 4 + (threadIdx.x >> 6);
    if (node >= n_nodes) return;
    float4 v = *(const float4*)(X + (size_t)node * IN_F + lane * 4);
    ushort4 o; o.x = f2bf(v.x); o.y = f2bf(v.y); o.z = f2bf(v.z); o.w = f2bf(v.w);
    *(ushort4*)(Xb + (size_t)node * IN_F + lane * 4) = o;

    float ps[HEADS], pd[HEADS];
#pragma unroll
    for (int hd = 0; hd < HEADS; ++hd) {
        float4 s4 = *(const float4*)(va_s + hd * IN_F + lane * 4);
        float4 d4 = *(const float4*)(va_d + hd * IN_F + lane * 4);
        ps[hd] = v.x * s4.x + v.y * s4.y + v.z * s4.z + v.w * s4.w;
        pd[hd] = v.x * d4.x + v.y * d4.y + v.z * d4.z + v.w * d4.w;
    }
#pragma unroll
    for (int off = 32; off > 0; off >>= 1) {
#pragma unroll
        for (int hd = 0; hd < HEADS; ++hd) {
            ps[hd] += __shfl_xor(ps[hd], off, 64);
            pd[hd] += __shfl_xor(pd[hd], off, 64);
        }
    }
    if (lane == 0) {
        float4 s4 = make_float4(ps[0], ps[1], ps[2], ps[3]);
        float4 d4 = make_float4(pd[0], pd[1], pd[2], pd[3]);
        *(float4*)(a_s + node * 4) = s4;
        *(float4*)(a_d + node * 4) = d4;
    }
}

// --------- bucket edges by dst: table[d][r] = src ---------
__global__ __launch_bounds__(256) void build_table(const int* __restrict__ src,
                                                   const int* __restrict__ dst,
                                                   int* __restrict__ cursor,
                                                   int* __restrict__ table,
                                                   int n_edges) {
    int e = blockIdx.x * blockDim.x + threadIdx.x;
    if (e >= n_edges) return;
    int d = dst[e];
    int r = atomicAdd(&cursor[d], 1);
    if (r < CAP) table[(size_t)d * CAP + r] = src[e];
}

// --------- fused softmax + X-space aggregation: wave per node ---------
// Aggregation commutes with the projection: Z[n][h] = rdv_h*(es_h*x_n + sum_e w_e^h * x_src).
// Gathers read 512B x-rows (half of the old 1KB h-rows) -> halves the L2-miss traffic
// that bounds this kernel. Projection moves to gemm2 afterwards (same FLOPs).
// Lane owns channels lane*4..lane*4+3 for ALL 4 heads (acc[4][4] fp32).
#define ACC8(U, WE)                                                         \
    {                                                                       \
        float f0 = bflo((U).x), f1 = bfhi((U).x);                           \
        float f2 = bflo((U).y), f3 = bfhi((U).y);                           \
        acc[0][0] = fmaf((WE).x, f0, acc[0][0]);                            \
        acc[0][1] = fmaf((WE).x, f1, acc[0][1]);                            \
        acc[0][2] = fmaf((WE).x, f2, acc[0][2]);                            \
        acc[0][3] = fmaf((WE).x, f3, acc[0][3]);                            \
        acc[1][0] = fmaf((WE).y, f0, acc[1][0]);                            \
        acc[1][1] = fmaf((WE).y, f1, acc[1][1]);                            \
        acc[1][2] = fmaf((WE).y, f2, acc[1][2]);                            \
        acc[1][3] = fmaf((WE).y, f3, acc[1][3]);                            \
        acc[2][0] = fmaf((WE).z, f0, acc[2][0]);                            \
        acc[2][1] = fmaf((WE).z, f1, acc[2][1]);                            \
        acc[2][2] = fmaf((WE).z, f2, acc[2][2]);                            \
        acc[2][3] = fmaf((WE).z, f3, acc[2][3]);                            \
        acc[3][0] = fmaf((WE).w, f0, acc[3][0]);                            \
        acc[3][1] = fmaf((WE).w, f1, acc[3][1]);                            \
        acc[3][2] = fmaf((WE).w, f2, acc[3][2]);                            \
        acc[3][3] = fmaf((WE).w, f3, acc[3][3]);                            \
    }

__global__ __launch_bounds__(256) void gat_agg(const ushort* __restrict__ Xb,
                                               const float* __restrict__ a_s,
                                               const float* __restrict__ a_d,
                                               const int* __restrict__ cursor,
                                               const int* __restrict__ table,
                                               ushort* __restrict__ Zb,
                                               int n_nodes) {
    __shared__ float4 wse[4][CAP];              // [wave][edge] -> (w_h0..w_h3)
    const int lane = threadIdx.x & 63;
    const int wid  = threadIdx.x >> 6;
    int n = blockIdx.x * 4 + wid;
    const bool valid = n < n_nodes;
    if (!valid) n = n_nodes - 1;                // clamp: keep all waves for barrier
    int deg = cursor[n]; if (deg > CAP) deg = CAP;
    const int* row = table + (size_t)n * CAP;

    // ---- softmax over self + in-edges (lane e owns edge e) ----
    const float4 ad4 = *(const float4*)(a_d + n * 4);
    const float4 as4 = *(const float4*)(a_s + n * 4);
    const float ad[4] = {ad4.x, ad4.y, ad4.z, ad4.w};
    float aself[4];
    {
        const float asn[4] = {as4.x, as4.y, as4.z, as4.w};
#pragma unroll
        for (int hd = 0; hd < 4; ++hd) {
            float al0 = asn[hd] + ad[hd];
            aself[hd] = al0 > 0.f ? al0 : NEG * al0;
        }
    }
    const bool act = lane < deg;
    float al[4];
    {
        int s = act ? row[lane] : 0;
        float4 av = *(const float4*)(a_s + s * 4);
        const float as_[4] = {av.x, av.y, av.z, av.w};
#pragma unroll
        for (int hd = 0; hd < 4; ++hd) {
            float a = as_[hd] + ad[hd];
            a = a > 0.f ? a : NEG * a;
            al[hd] = act ? a : -1e30f;
        }
    }
    float m[4];
#pragma unroll
    for (int hd = 0; hd < 4; ++hd) m[hd] = al[hd];
#pragma unroll
    for (int off = 32; off > 0; off >>= 1)
#pragma unroll
        for (int hd = 0; hd < 4; ++hd)
            m[hd] = fmaxf(m[hd], __shfl_xor(m[hd], off, 64));
#pragma unroll
    for (int hd = 0; hd < 4; ++hd) m[hd] = fmaxf(m[hd], aself[hd]);

    float w[4], den[4];
#pragma unroll
    for (int hd = 0; hd < 4; ++hd) {
        w[hd] = act ? __expf(al[hd] - m[hd]) : 0.f;
        den[hd] = w[hd];
    }
#pragma unroll
    for (int off = 32; off > 0; off >>= 1)
#pragma unroll
        for (int hd = 0; hd < 4; ++hd)
            den[hd] += __shfl_xor(den[hd], off, 64);

    float es[4], rdv[4];
#pragma unroll
    for (int hd = 0; hd < 4; ++hd) {
        es[hd] = __expf(aself[hd] - m[hd]);
        rdv[hd] = 1.f / (den[hd] + es[hd]);
    }

    // publish per-edge weights edge-major (float4 of 4 heads; w=0 for lanes >= deg)
    wse[wid][lane] = make_float4(w[0], w[1], w[2], w[3]);
    __syncthreads();

    // ---- aggregation over x rows: lane owns 4 channels x 4 heads ----
    const uint2* xb2 = (const uint2*)Xb;        // one node row = 64 uint2 (512B)
    float acc[4][4];
    {
        uint2 u = xb2[(size_t)n * 64 + lane];
        float f0 = bflo(u.x), f1 = bfhi(u.x), f2 = bflo(u.y), f3 = bfhi(u.y);
#pragma unroll
        for (int hd = 0; hd < 4; ++hd) {
            acc[hd][0] = es[hd] * f0;
            acc[hd][1] = es[hd] * f1;
            acc[hd][2] = es[hd] * f2;
            acc[hd][3] = es[hd] * f3;
        }
    }
    int e = 0;
    for (; e + 8 <= deg; e += 8) {
        int4 ra = *(const int4*)(row + e);
        int4 rb = *(const int4*)(row + e + 4);
        uint2 u0 = xb2[(size_t)ra.x * 64 + lane];
        uint2 u1 = xb2[(size_t)ra.y * 64 + lane];
        uint2 u2 = xb2[(size_t)ra.z * 64 + lane];
        uint2 u3 = xb2[(size_t)ra.w * 64 + lane];
        uint2 u4 = xb2[(size_t)rb.x * 64 + lane];
        uint2 u5 = xb2[(size_t)rb.y * 64 + lane];
        uint2 u6 = xb2[(size_t)rb.z * 64 + lane];
        uint2 u7 = xb2[(size_t)rb.w * 64 + lane];
        float4 w0 = wse[wid][e + 0]; float4 w1 = wse[wid][e + 1];
        float4 w2 = wse[wid][e + 2]; float4 w3 = wse[wid][e + 3];
        float4 w4 = wse[wid][e + 4]; float4 w5 = wse[wid][e + 5];
        float4 w6 = wse[wid][e + 6]; float4 w7 = wse[wid][e + 7];
        ACC8(u0, w0); ACC8(u1, w1); ACC8(u2, w2); ACC8(u3, w3);
        ACC8(u4, w4); ACC8(u5, w5); ACC8(u6, w6); ACC8(u7, w7);
    }
    for (; e < deg; ++e) {
        uint2 u = xb2[(size_t)row[e] * 64 + lane];
        float4 we = wse[wid][e];
        ACC8(u, we);
    }

    if (valid) {
        ushort* zr = Zb + (size_t)n * K2;
#pragma unroll
        for (int hd = 0; hd < 4; ++hd) {
            ushort4 z;
            z.x = f2bf(acc[hd][0] * rdv[hd]);
            z.y = f2bf(acc[hd][1] * rdv[hd]);
            z.z = f2bf(acc[hd][2] * rdv[hd]);
            z.w = f2bf(acc[hd][3] * rdv[hd]);
            *(ushort4*)(zr + hd * 256 + lane * 4) = z;
        }
    }
}

// ---------------- out = tanh(0.25 * Zb @ WT2^T + bias), bf16 MFMA, K=1024 ----------------
#define GBM 128
#define GBN 128
#define GBK 32

__global__ __launch_bounds__(256) void gemm2(const ushort* __restrict__ Zb,
                                             const ushort* __restrict__ WT2,
                                             const float* __restrict__ bias,
                                             float* __restrict__ out,
                                             int n_nodes) {
    __shared__ ushort As[GBM][GBK];
    __shared__ ushort Bs[GBN][GBK];
    const int tid = threadIdx.x;
    const int m0 = blockIdx.y * GBM;
    const int n0 = blockIdx.x * GBN;                // == 0 (grid.x = 1)
    const int wave = tid >> 6, lane = tid & 63;
    const int wm = (wave & 1) * 64, wn = (wave >> 1) * 64;
    const int l15 = lane & 15, quad = lane >> 4;

    const int rr = lane >> 2;
    const int cg = (lane & 3) ^ ((lane >> 3) & 3);
    const int rA = wave * 16 + rr;
    const ushort* gA0 = Zb + (size_t)(m0 + rA) * K2 + cg * 8;
    const ushort* gA1 = Zb + (size_t)(m0 + 64 + rA) * K2 + cg * 8;
    const ushort* gB0 = WT2 + (size_t)(n0 + rA) * K2 + cg * 8;
    const ushort* gB1 = WT2 + (size_t)(n0 + 64 + rA) * K2 + cg * 8;
    ushort* lA0 = &As[wave * 16][0];
    ushort* lA1 = &As[64 + wave * 16][0];
    ushort* lB0 = &Bs[wave * 16][0];
    ushort* lB1 = &Bs[64 + wave * 16][0];

    f32x4 acc[4][4];
#pragma unroll
    for (int i = 0; i < 4; ++i)
#pragma unroll
        for (int j = 0; j < 4; ++j) acc[i][j] = (f32x4){0.f, 0.f, 0.f, 0.f};

    const int ks = (quad ^ ((l15 >> 1) & 3)) * 8;

    for (int k0 = 0; k0 < K2; k0 += GBK) {
        __syncthreads();
        __builtin_amdgcn_global_load_lds((gp_t)(gA0 + k0), (lp_t)lA0, 16, 0, 0);
        __builtin_amdgcn_global_load_lds((gp_t)(gA1 + k0), (lp_t)lA1, 16, 0, 0);
        __builtin_amdgcn_global_load_lds((gp_t)(gB0 + k0), (lp_t)lB0, 16, 0, 0);
        __builtin_amdgcn_global_load_lds((gp_t)(gB1 + k0), (lp_t)lB1, 16, 0, 0);
        __syncthreads();

        short8 af[4], bf_[4];
#pragma unroll
        for (int f = 0; f < 4; ++f) {
            af[f]  = *(const short8*)&As[wm + f * 16 + l15][ks];
            bf_[f] = *(const short8*)&Bs[wn + f * 16 + l15][ks];
        }
#pragma unroll
        for (int fm = 0; fm < 4; ++fm)
#pragma unroll
            for (int fn = 0; fn < 4; ++fn)
                acc[fm][fn] = __builtin_amdgcn_mfma_f32_16x16x32_bf16(
                    af[fm], bf_[fn], acc[fm][fn], 0, 0, 0);
    }

    float bcol[4];
#pragma unroll
    for (int fn = 0; fn < 4; ++fn) bcol[fn] = bias[wn + fn * 16 + l15];

#pragma unroll
    for (int fm = 0; fm < 4; ++fm) {
        int gmb = m0 + wm + fm * 16 + quad * 4;
#pragma unroll
        for (int reg = 0; reg < 4; ++reg) {
            int gm = gmb + reg;
            if (gm < n_nodes) {
#pragma unroll
                for (int fn = 0; fn < 4; ++fn) {
                    float o = tanhf(0.25f * acc[fm][fn][reg] + bcol[fn]);
                    out[(size_t)gm * OUT_F + wn + fn * 16 + l15] = o;
                }
            }
        }
    }
}

extern "C" void kernel_launch(void* const* d_in, const int* in_sizes, int n_in,
                              void* d_out, int out_size, void* d_ws, size_t ws_size,
                              hipStream_t stream) {
    const float* x       = (const float*)d_in[0];
    const int*   ei      = (const int*)d_in[1];
    const float* W       = (const float*)d_in[2];
    const float* att_src = (const float*)d_in[3];
    const float* att_dst = (const float*)d_in[4];
    const float* bias    = (const float*)d_in[5];
    float* out = (float*)d_out;

    const int n_nodes = in_sizes[0] / IN_F;     // 30000
    const int n_edges = in_sizes[1] / 2;        // 480000
    const int* src = ei;
    const int* dst = ei + n_edges;

    char* ws = (char*)d_ws;
    size_t off = 0;
    auto alloc = [&](size_t bytes) -> void* {
        void* p = ws + off;
        off = (off + bytes + 255) & ~(size_t)255;
        return p;
    };
    ushort* Xb     = (ushort*)alloc((size_t)n_nodes * IN_F * sizeof(ushort));   // 15.4 MB
    ushort* Zb     = (ushort*)alloc((size_t)n_nodes * K2 * sizeof(ushort));     // 61.4 MB
    ushort* WT2    = (ushort*)alloc((size_t)OUT_F * K2 * sizeof(ushort));       // 0.26 MB (also Zb tail-overread pad)
    float*  va_s   = (float*)alloc((size_t)HEADS * IN_F * sizeof(float));
    float*  va_d   = (float*)alloc((size_t)HEADS * IN_F * sizeof(float));
    float*  a_s    = (float*)alloc((size_t)n_nodes * HEADS * sizeof(float));
    float*  a_d    = (float*)alloc((size_t)n_nodes * HEADS * sizeof(float));
    int*    cursor = (int*)alloc((size_t)n_nodes * sizeof(int));
    int*    table  = (int*)alloc((size_t)n_nodes * CAP * sizeof(int));          // 7.7 MB
    (void)ws_size; (void)n_in; (void)out_size;

    hipMemsetAsync(cursor, 0, (size_t)n_nodes * sizeof(int), stream);

    cvt_wt2<<<(OUT_F * K2) / 256, 256, 0, stream>>>(W, WT2);
    calc_va<<<(HEADS * IN_F) / 4, 256, 0, stream>>>(W, att_src, att_dst, va_s, va_d);
    fused_x<<<(n_nodes + 3) / 4, 256, 0, stream>>>(x, va_s, va_d, Xb, a_s, a_d, n_nodes);
    build_table<<<(n_edges + 255) / 256, 256, 0, stream>>>(src, dst, cursor, table, n_edges);

    gat_agg<<<(n_nodes + 3) / 4, 256, 0, stream>>>(Xb, a_s, a_d, cursor, table,
                                                   Zb, n_nodes);

    dim3 ggrid(1, (n_nodes + GBM - 1) / GBM);   // 1 x 235
    gemm2<<<ggrid, 256, 0, stream>>>(Zb, WT2, bias, out, n_nodes);
}

// Round 4
// 206.624 us; speedup vs baseline: 1.1162x; 1.0499x over previous
//
#include <hip/hip_runtime.h>
#include <math.h>

#define IN_F   256
#define OUT_F  128
#define HEADS  4
#define HD     (HEADS * OUT_F)   // 512
#define K2     1024              // stacked contraction: 4 heads x 256
#define NEG    0.2f
#define CAP    64                // per-node in-edge capacity (mean deg 16; P(deg>64) ~ 1e-18)

typedef __attribute__((ext_vector_type(8))) short short8;   // 8 bf16 = 4 VGPRs
typedef __attribute__((ext_vector_type(4))) float f32x4;

typedef __attribute__((address_space(1))) const void* gp_t;
typedef __attribute__((address_space(3))) void* lp_t;

static __device__ __forceinline__ ushort f2bf(float f) {
    union { float f; unsigned u; } v; v.f = f;
    unsigned r = (v.u + 0x7FFFu + ((v.u >> 16) & 1u)) >> 16;   // RNE
    return (ushort)r;
}
static __device__ __forceinline__ float bflo(unsigned u) {
    union { unsigned u; float f; } v; v.u = u << 16; return v.f;
}
static __device__ __forceinline__ float bfhi(unsigned u) {
    union { unsigned u; float f; } v; v.u = u & 0xFFFF0000u; return v.f;
}

// ---------------- prep: fused cvt_wt2 + calc_va + build_table (role by blockIdx) ----------------
// blocks [0,512)        : WT2[cout][h*256+c] = bf16(W[c][h*128+cout])
// blocks [512,768)      : va = W @ att  (wave per (h,k); butterfly reduce)
// blocks [768, 768+nebk): bucket edges by dst
__global__ __launch_bounds__(256) void prep(const float* __restrict__ W,
                                            const float* __restrict__ att_src,
                                            const float* __restrict__ att_dst,
                                            const int* __restrict__ src,
                                            const int* __restrict__ dst,
                                            ushort* __restrict__ WT2,
                                            float* __restrict__ va_s,
                                            float* __restrict__ va_d,
                                            int* __restrict__ cursor,
                                            int* __restrict__ table,
                                            int n_edges) {
    const int b = blockIdx.x;
    const int tid = threadIdx.x;
    if (b < 512) {
        int idx = b * 256 + tid;               // 128*1024
        int cout = idx >> 10, kk = idx & 1023;
        int h = kk >> 8, c = kk & 255;
        WT2[idx] = f2bf(W[(size_t)c * HD + h * OUT_F + cout]);
    } else if (b < 768) {
        const int lane = tid & 63;
        const int p = (b - 512) * 4 + (tid >> 6);   // 0..1023 = h*256 + k
        const int h = p >> 8;
        const int k = p & 255;
        const float* wr = W + (size_t)k * HD + h * OUT_F;
        float w0 = wr[lane], w1 = wr[lane + 64];
        float s0 = att_src[h * OUT_F + lane], s1 = att_src[h * OUT_F + lane + 64];
        float d0 = att_dst[h * OUT_F + lane], d1 = att_dst[h * OUT_F + lane + 64];
        float ss = w0 * s0 + w1 * s1;
        float sd = w0 * d0 + w1 * d1;
#pragma unroll
        for (int off = 32; off > 0; off >>= 1) {
            ss += __shfl_xor(ss, off, 64);
            sd += __shfl_xor(sd, off, 64);
        }
        if (lane == 0) { va_s[p] = ss; va_d[p] = sd; }
    } else {
        int e = (b - 768) * 256 + tid;
        if (e < n_edges) {
            int d = dst[e];
            int r = atomicAdd(&cursor[d], 1);
            if (r < CAP) table[(size_t)d * CAP + r] = src[e];
        }
    }
}

// ------- fused: X f32 -> Xb bf16, plus a_s/a_d = x . va (wave per node) -------
__global__ __launch_bounds__(256) void fused_x(const float* __restrict__ X,
                                               const float* __restrict__ va_s,
                                               const float* __restrict__ va_d,
                                               ushort* __restrict__ Xb,
                                               float* __restrict__ a_s,
                                               float* __restrict__ a_d,
                                               int n_nodes) {
    const int lane = threadIdx.x & 63;
    const int node = blockIdx.x * 4 + (threadIdx.x >> 6);
    if (node >= n_nodes) return;
    float4 v = *(const float4*)(X + (size_t)node * IN_F + lane * 4);
    ushort4 o; o.x = f2bf(v.x); o.y = f2bf(v.y); o.z = f2bf(v.z); o.w = f2bf(v.w);
    *(ushort4*)(Xb + (size_t)node * IN_F + lane * 4) = o;

    float ps[HEADS], pd[HEADS];
#pragma unroll
    for (int hd = 0; hd < HEADS; ++hd) {
        float4 s4 = *(const float4*)(va_s + hd * IN_F + lane * 4);
        float4 d4 = *(const float4*)(va_d + hd * IN_F + lane * 4);
        ps[hd] = v.x * s4.x + v.y * s4.y + v.z * s4.z + v.w * s4.w;
        pd[hd] = v.x * d4.x + v.y * d4.y + v.z * d4.z + v.w * d4.w;
    }
#pragma unroll
    for (int off = 32; off > 0; off >>= 1) {
#pragma unroll
        for (int hd = 0; hd < HEADS; ++hd) {
            ps[hd] += __shfl_xor(ps[hd], off, 64);
            pd[hd] += __shfl_xor(pd[hd], off, 64);
        }
    }
    if (lane == 0) {
        float4 s4 = make_float4(ps[0], ps[1], ps[2], ps[3]);
        float4 d4 = make_float4(pd[0], pd[1], pd[2], pd[3]);
        *(float4*)(a_s + node * 4) = s4;
        *(float4*)(a_d + node * 4) = d4;
    }
}

// --------- fused softmax + X-space aggregation: wave per node ---------
// Z[n][h] = rdv_h*(es_h*x_n + sum_e w_e^h * x_src). Lane owns 4 channels x 4 heads.
// Gather addresses come from REGISTER shuffles (lane e holds src[e] from the softmax
// phase) instead of re-loading row[] from global -> removes the ~600cy address chain.
// Group-0 gathers + self row are issued BEFORE the softmax butterflies (latency hidden),
// and groups are explicitly double-buffered (issue g+1 before FMAs of g).
#define ACC8(U, WE)                                                         \
    {                                                                       \
        float f0 = bflo((U).x), f1 = bfhi((U).x);                           \
        float f2 = bflo((U).y), f3 = bfhi((U).y);                           \
        acc[0][0] = fmaf((WE).x, f0, acc[0][0]);                            \
        acc[0][1] = fmaf((WE).x, f1, acc[0][1]);                            \
        acc[0][2] = fmaf((WE).x, f2, acc[0][2]);                            \
        acc[0][3] = fmaf((WE).x, f3, acc[0][3]);                            \
        acc[1][0] = fmaf((WE).y, f0, acc[1][0]);                            \
        acc[1][1] = fmaf((WE).y, f1, acc[1][1]);                            \
        acc[1][2] = fmaf((WE).y, f2, acc[1][2]);                            \
        acc[1][3] = fmaf((WE).y, f3, acc[1][3]);                            \
        acc[2][0] = fmaf((WE).z, f0, acc[2][0]);                            \
        acc[2][1] = fmaf((WE).z, f1, acc[2][1]);                            \
        acc[2][2] = fmaf((WE).z, f2, acc[2][2]);                            \
        acc[2][3] = fmaf((WE).z, f3, acc[2][3]);                            \
        acc[3][0] = fmaf((WE).w, f0, acc[3][0]);                            \
        acc[3][1] = fmaf((WE).w, f1, acc[3][1]);                            \
        acc[3][2] = fmaf((WE).w, f2, acc[3][2]);                            \
        acc[3][3] = fmaf((WE).w, f3, acc[3][3]);                            \
    }

#define GATHER8(E, D0, D1, D2, D3, D4, D5, D6, D7)                          \
    {                                                                       \
        int t0 = __shfl(sreg, (E) + 0, 64);                                 \
        int t1 = __shfl(sreg, (E) + 1, 64);                                 \
        int t2 = __shfl(sreg, (E) + 2, 64);                                 \
        int t3 = __shfl(sreg, (E) + 3, 64);                                 \
        int t4 = __shfl(sreg, (E) + 4, 64);                                 \
        int t5 = __shfl(sreg, (E) + 5, 64);                                 \
        int t6 = __shfl(sreg, (E) + 6, 64);                                 \
        int t7 = __shfl(sreg, (E) + 7, 64);                                 \
        D0 = xb2[(size_t)t0 * 64 + lane];                                   \
        D1 = xb2[(size_t)t1 * 64 + lane];                                   \
        D2 = xb2[(size_t)t2 * 64 + lane];                                   \
        D3 = xb2[(size_t)t3 * 64 + lane];                                   \
        D4 = xb2[(size_t)t4 * 64 + lane];                                   \
        D5 = xb2[(size_t)t5 * 64 + lane];                                   \
        D6 = xb2[(size_t)t6 * 64 + lane];                                   \
        D7 = xb2[(size_t)t7 * 64 + lane];                                   \
    }

__global__ __launch_bounds__(256) void gat_agg(const ushort* __restrict__ Xb,
                                               const float* __restrict__ a_s,
                                               const float* __restrict__ a_d,
                                               const int* __restrict__ cursor,
                                               const int* __restrict__ table,
                                               ushort* __restrict__ Zb,
                                               int n_nodes) {
    __shared__ float4 wse[4][CAP];              // [wave][edge] -> (w_h0..w_h3)
    const int lane = threadIdx.x & 63;
    const int wid  = threadIdx.x >> 6;
    int n = blockIdx.x * 4 + wid;
    const bool valid = n < n_nodes;
    if (!valid) n = n_nodes - 1;                // clamp: keep all waves for barrier
    int deg = cursor[n]; if (deg > CAP) deg = CAP;
    const int* row = table + (size_t)n * CAP;
    const bool act = lane < deg;
    int sreg = act ? row[lane] : n;             // lane e holds src[e] (self if inactive)

    const uint2* xb2 = (const uint2*)Xb;        // one node row = 64 uint2 (512B)
    uint2 uself = xb2[(size_t)n * 64 + lane];   // prefetch self row

    const int ngroups = (deg + 7) >> 3;
    uint2 ua0, ua1, ua2, ua3, ua4, ua5, ua6, ua7;
    if (ngroups > 0) GATHER8(0, ua0, ua1, ua2, ua3, ua4, ua5, ua6, ua7);

    // ---- softmax over self + in-edges (lane e owns edge e); gathers in flight ----
    const float4 ad4 = *(const float4*)(a_d + n * 4);
    const float4 as4 = *(const float4*)(a_s + n * 4);
    const float ad[4] = {ad4.x, ad4.y, ad4.z, ad4.w};
    float aself[4];
    {
        const float asn[4] = {as4.x, as4.y, as4.z, as4.w};
#pragma unroll
        for (int hd = 0; hd < 4; ++hd) {
            float al0 = asn[hd] + ad[hd];
            aself[hd] = al0 > 0.f ? al0 : NEG * al0;
        }
    }
    float al[4];
    {
        float4 av = *(const float4*)(a_s + (size_t)sreg * 4);
        const float as_[4] = {av.x, av.y, av.z, av.w};
#pragma unroll
        for (int hd = 0; hd < 4; ++hd) {
            float a = as_[hd] + ad[hd];
            a = a > 0.f ? a : NEG * a;
            al[hd] = act ? a : -1e30f;
        }
    }
    float m[4];
#pragma unroll
    for (int hd = 0; hd < 4; ++hd) m[hd] = al[hd];
#pragma unroll
    for (int off = 32; off > 0; off >>= 1)
#pragma unroll
        for (int hd = 0; hd < 4; ++hd)
            m[hd] = fmaxf(m[hd], __shfl_xor(m[hd], off, 64));
#pragma unroll
    for (int hd = 0; hd < 4; ++hd) m[hd] = fmaxf(m[hd], aself[hd]);

    float w[4], den[4];
#pragma unroll
    for (int hd = 0; hd < 4; ++hd) {
        w[hd] = act ? __expf(al[hd] - m[hd]) : 0.f;
        den[hd] = w[hd];
    }
#pragma unroll
    for (int off = 32; off > 0; off >>= 1)
#pragma unroll
        for (int hd = 0; hd < 4; ++hd)
            den[hd] += __shfl_xor(den[hd], off, 64);

    float es[4], rdv[4];
#pragma unroll
    for (int hd = 0; hd < 4; ++hd) {
        es[hd] = __expf(aself[hd] - m[hd]);
        rdv[hd] = 1.f / (den[hd] + es[hd]);
    }

    // publish per-edge weights (w=0 for lanes >= deg)
    wse[wid][lane] = make_float4(w[0], w[1], w[2], w[3]);
    __syncthreads();

    // ---- aggregation: double-buffered 8-edge groups ----
    float acc[4][4];
    {
        float f0 = bflo(uself.x), f1 = bfhi(uself.x);
        float f2 = bflo(uself.y), f3 = bfhi(uself.y);
#pragma unroll
        for (int hd = 0; hd < 4; ++hd) {
            acc[hd][0] = es[hd] * f0;
            acc[hd][1] = es[hd] * f1;
            acc[hd][2] = es[hd] * f2;
            acc[hd][3] = es[hd] * f3;
        }
    }
#pragma unroll 1
    for (int g = 0; g < ngroups; ++g) {
        int e = g * 8;
        uint2 ub0, ub1, ub2, ub3, ub4, ub5, ub6, ub7;
        if (g + 1 < ngroups)
            GATHER8(e + 8, ub0, ub1, ub2, ub3, ub4, ub5, ub6, ub7);
        float4 w0 = wse[wid][e + 0]; float4 w1 = wse[wid][e + 1];
        float4 w2 = wse[wid][e + 2]; float4 w3 = wse[wid][e + 3];
        float4 w4 = wse[wid][e + 4]; float4 w5 = wse[wid][e + 5];
        float4 w6 = wse[wid][e + 6]; float4 w7 = wse[wid][e + 7];
        ACC8(ua0, w0); ACC8(ua1, w1); ACC8(ua2, w2); ACC8(ua3, w3);
        ACC8(ua4, w4); ACC8(ua5, w5); ACC8(ua6, w6); ACC8(ua7, w7);
        if (g + 1 < ngroups) {
            ua0 = ub0; ua1 = ub1; ua2 = ub2; ua3 = ub3;
            ua4 = ub4; ua5 = ub5; ua6 = ub6; ua7 = ub7;
        }
    }

    if (valid) {
        ushort* zr = Zb + (size_t)n * K2;
#pragma unroll
        for (int hd = 0; hd < 4; ++hd) {
            ushort4 z;
            z.x = f2bf(acc[hd][0] * rdv[hd]);
            z.y = f2bf(acc[hd][1] * rdv[hd]);
            z.z = f2bf(acc[hd][2] * rdv[hd]);
            z.w = f2bf(acc[hd][3] * rdv[hd]);
            *(ushort4*)(zr + hd * 256 + lane * 4) = z;
        }
    }
}

// ---------------- out = tanh(0.25 * Zb @ WT2^T + bias), bf16 MFMA, K=1024 ----------------
// Tile 64x128, GBK=64 -> 469 blocks (full CU coverage), 16 barrier-drains (vs 32).
// LDS rows = 64 ushorts (8 chunks of 16B); chunk slot s of row r holds global chunk
// s ^ (r&7) (pre-swizzled global source; DMA dest stays linear). Fragment read slot
// = (t*4+quad) ^ (l15&7): 16 lanes/quad spread over 8 bank-groups -> 2-way (free).
#define GBM 64
#define GBN 128
#define GBK 64

__global__ __launch_bounds__(256) void gemm2(const ushort* __restrict__ Zb,
                                             const ushort* __restrict__ WT2,
                                             const float* __restrict__ bias,
                                             float* __restrict__ out,
                                             int n_nodes) {
    __shared__ ushort As[GBM][GBK];             // 8 KB
    __shared__ ushort Bs[GBN][GBK];             // 16 KB
    const int tid = threadIdx.x;
    const int m0 = blockIdx.y * GBM;
    const int wave = tid >> 6, lane = tid & 63;
    const int wm = (wave & 1) * 32, wn = (wave >> 1) * 64;
    const int l15 = lane & 15, quad = lane >> 4;

    // staging: per instr a wave covers 8 rows (lane>>3), chunk slot lane&7.
    const int rr8 = lane >> 3;
    const int cg  = (lane & 7) ^ rr8;           // pre-swizzled global chunk
    const ushort* gA0 = Zb + (size_t)(m0 + wave * 16 + rr8) * K2 + cg * 8;
    const ushort* gA1 = gA0 + 8 * K2;
    const ushort* gB0 = WT2 + (size_t)(wave * 32 + rr8) * K2 + cg * 8;
    const ushort* gB1 = gB0 + 8 * K2;
    const ushort* gB2 = gB0 + 16 * K2;
    const ushort* gB3 = gB0 + 24 * K2;
    ushort* lA0 = &As[wave * 16][0];
    ushort* lA1 = &As[wave * 16 + 8][0];
    ushort* lB0 = &Bs[wave * 32][0];
    ushort* lB1 = &Bs[wave * 32 + 8][0];
    ushort* lB2 = &Bs[wave * 32 + 16][0];
    ushort* lB3 = &Bs[wave * 32 + 24][0];

    f32x4 acc[2][4];
#pragma unroll
    for (int i = 0; i < 2; ++i)
#pragma unroll
        for (int j = 0; j < 4; ++j) acc[i][j] = (f32x4){0.f, 0.f, 0.f, 0.f};

    for (int k0 = 0; k0 < K2; k0 += GBK) {
        __syncthreads();
        __builtin_amdgcn_global_load_lds((gp_t)(gA0 + k0), (lp_t)lA0, 16, 0, 0);
        __builtin_amdgcn_global_load_lds((gp_t)(gA1 + k0), (lp_t)lA1, 16, 0, 0);
        __builtin_amdgcn_global_load_lds((gp_t)(gB0 + k0), (lp_t)lB0, 16, 0, 0);
        __builtin_amdgcn_global_load_lds((gp_t)(gB1 + k0), (lp_t)lB1, 16, 0, 0);
        __builtin_amdgcn_global_load_lds((gp_t)(gB2 + k0), (lp_t)lB2, 16, 0, 0);
        __builtin_amdgcn_global_load_lds((gp_t)(gB3 + k0), (lp_t)lB3, 16, 0, 0);
        __syncthreads();

#pragma unroll
        for (int t = 0; t < 2; ++t) {
            const int sl = ((t * 4 + quad) ^ (l15 & 7)) * 8;
            short8 af[2], bf_[4];
#pragma unroll
            for (int fm = 0; fm < 2; ++fm)
                af[fm] = *(const short8*)&As[wm + fm * 16 + l15][sl];
#pragma unroll
            for (int fn = 0; fn < 4; ++fn)
                bf_[fn] = *(const short8*)&Bs[wn + fn * 16 + l15][sl];
#pragma unroll
            for (int fm = 0; fm < 2; ++fm)
#pragma unroll
                for (int fn = 0; fn < 4; ++fn)
                    acc[fm][fn] = __builtin_amdgcn_mfma_f32_16x16x32_bf16(
                        af[fm], bf_[fn], acc[fm][fn], 0, 0, 0);
        }
    }

    float bcol[4];
#pragma unroll
    for (int fn = 0; fn < 4; ++fn) bcol[fn] = bias[wn + fn * 16 + l15];

#pragma unroll
    for (int fm = 0; fm < 2; ++fm) {
        int gmb = m0 + wm + fm * 16 + quad * 4;
#pragma unroll
        for (int reg = 0; reg < 4; ++reg) {
            int gm = gmb + reg;
            if (gm < n_nodes) {
#pragma unroll
                for (int fn = 0; fn < 4; ++fn) {
                    float o = tanhf(0.25f * acc[fm][fn][reg] + bcol[fn]);
                    out[(size_t)gm * OUT_F + wn + fn * 16 + l15] = o;
                }
            }
        }
    }
}

extern "C" void kernel_launch(void* const* d_in, const int* in_sizes, int n_in,
                              void* d_out, int out_size, void* d_ws, size_t ws_size,
                              hipStream_t stream) {
    const float* x       = (const float*)d_in[0];
    const int*   ei      = (const int*)d_in[1];
    const float* W       = (const float*)d_in[2];
    const float* att_src = (const float*)d_in[3];
    const float* att_dst = (const float*)d_in[4];
    const float* bias    = (const float*)d_in[5];
    float* out = (float*)d_out;

    const int n_nodes = in_sizes[0] / IN_F;     // 30000
    const int n_edges = in_sizes[1] / 2;        // 480000
    const int* src = ei;
    const int* dst = ei + n_edges;

    char* ws = (char*)d_ws;
    size_t off = 0;
    auto alloc = [&](size_t bytes) -> void* {
        void* p = ws + off;
        off = (off + bytes + 255) & ~(size_t)255;
        return p;
    };
    ushort* Xb     = (ushort*)alloc((size_t)n_nodes * IN_F * sizeof(ushort));   // 15.4 MB
    ushort* Zb     = (ushort*)alloc((size_t)n_nodes * K2 * sizeof(ushort));     // 61.4 MB
    ushort* WT2    = (ushort*)alloc((size_t)OUT_F * K2 * sizeof(ushort));       // 0.26 MB (also Zb tail-overread pad)
    float*  va_s   = (float*)alloc((size_t)HEADS * IN_F * sizeof(float));
    float*  va_d   = (float*)alloc((size_t)HEADS * IN_F * sizeof(float));
    float*  a_s    = (float*)alloc((size_t)n_nodes * HEADS * sizeof(float));
    float*  a_d    = (float*)alloc((size_t)n_nodes * HEADS * sizeof(float));
    int*    cursor = (int*)alloc((size_t)n_nodes * sizeof(int));
    int*    table  = (int*)alloc((size_t)n_nodes * CAP * sizeof(int));          // 7.7 MB
    (void)ws_size; (void)n_in; (void)out_size;

    hipMemsetAsync(cursor, 0, (size_t)n_nodes * sizeof(int), stream);

    const int nebk = (n_edges + 255) / 256;     // 1875
    prep<<<768 + nebk, 256, 0, stream>>>(W, att_src, att_dst, src, dst,
                                         WT2, va_s, va_d, cursor, table, n_edges);
    fused_x<<<(n_nodes + 3) / 4, 256, 0, stream>>>(x, va_s, va_d, Xb, a_s, a_d, n_nodes);
    gat_agg<<<(n_nodes + 3) / 4, 256, 0, stream>>>(Xb, a_s, a_d, cursor, table,
                                                   Zb, n_nodes);

    dim3 ggrid(1, (n_nodes + GBM - 1) / GBM);   // 1 x 469
    gemm2<<<ggrid, 256, 0, stream>>>(Zb, WT2, bias, out, n_nodes);
}

// Round 5
// 195.337 us; speedup vs baseline: 1.1807x; 1.0578x over previous
//
#include <hip/hip_runtime.h>
#include <math.h>

#define IN_F   256
#define OUT_F  128
#define HEADS  4
#define HD     (HEADS * OUT_F)   // 512
#define K2     1024              // stacked contraction: 4 heads x 256
#define NEG    0.2f
#define CAP    64                // per-node in-edge capacity (mean deg 16; P(deg>64) ~ 1e-18)

typedef __attribute__((ext_vector_type(8))) short short8;   // 8 bf16 = 4 VGPRs
typedef __attribute__((ext_vector_type(4))) float f32x4;
typedef __attribute__((ext_vector_type(2))) float f32x2;

typedef __attribute__((address_space(1))) const void* gp_t;
typedef __attribute__((address_space(3))) void* lp_t;

static __device__ __forceinline__ ushort f2bf(float f) {
    union { float f; unsigned u; } v; v.f = f;
    unsigned r = (v.u + 0x7FFFu + ((v.u >> 16) & 1u)) >> 16;   // RNE
    return (ushort)r;
}
static __device__ __forceinline__ float bflo(unsigned u) {
    union { unsigned u; float f; } v; v.u = u << 16; return v.f;
}
static __device__ __forceinline__ float bfhi(unsigned u) {
    union { unsigned u; float f; } v; v.u = u & 0xFFFF0000u; return v.f;
}

// packed fp32 FMA: D = A*B + D (per 32-bit half)
#define PKFMA(D, A, B) asm("v_pk_fma_f32 %0, %1, %2, %0" : "+v"(D) : "v"(A), "v"(B))

// ---------------- prep: fused cvt_wt2 + calc_va + build_table (role by blockIdx) ----------------
__global__ __launch_bounds__(256) void prep(const float* __restrict__ W,
                                            const float* __restrict__ att_src,
                                            const float* __restrict__ att_dst,
                                            const int* __restrict__ src,
                                            const int* __restrict__ dst,
                                            ushort* __restrict__ WT2,
                                            float* __restrict__ va_s,
                                            float* __restrict__ va_d,
                                            int* __restrict__ cursor,
                                            int* __restrict__ table,
                                            int n_edges) {
    const int b = blockIdx.x;
    const int tid = threadIdx.x;
    if (b < 512) {
        int idx = b * 256 + tid;               // 128*1024
        int cout = idx >> 10, kk = idx & 1023;
        int h = kk >> 8, c = kk & 255;
        WT2[idx] = f2bf(W[(size_t)c * HD + h * OUT_F + cout]);
    } else if (b < 768) {
        const int lane = tid & 63;
        const int p = (b - 512) * 4 + (tid >> 6);   // 0..1023 = h*256 + k
        const int h = p >> 8;
        const int k = p & 255;
        const float* wr = W + (size_t)k * HD + h * OUT_F;
        float w0 = wr[lane], w1 = wr[lane + 64];
        float s0 = att_src[h * OUT_F + lane], s1 = att_src[h * OUT_F + lane + 64];
        float d0 = att_dst[h * OUT_F + lane], d1 = att_dst[h * OUT_F + lane + 64];
        float ss = w0 * s0 + w1 * s1;
        float sd = w0 * d0 + w1 * d1;
#pragma unroll
        for (int off = 32; off > 0; off >>= 1) {
            ss += __shfl_xor(ss, off, 64);
            sd += __shfl_xor(sd, off, 64);
        }
        if (lane == 0) { va_s[p] = ss; va_d[p] = sd; }
    } else {
        int e = (b - 768) * 256 + tid;
        if (e < n_edges) {
            int d = dst[e];
            int r = atomicAdd(&cursor[d], 1);
            if (r < CAP) table[(size_t)d * CAP + r] = src[e];
        }
    }
}

// ------- fused: X f32 -> Xb bf16, plus a_s/a_d = x . va (wave per node) -------
__global__ __launch_bounds__(256) void fused_x(const float* __restrict__ X,
                                               const float* __restrict__ va_s,
                                               const float* __restrict__ va_d,
                                               ushort* __restrict__ Xb,
                                               float* __restrict__ a_s,
                                               float* __restrict__ a_d,
                                               int n_nodes) {
    const int lane = threadIdx.x & 63;
    const int node = blockIdx.x * 4 + (threadIdx.x >> 6);
    if (node >= n_nodes) return;
    float4 v = *(const float4*)(X + (size_t)node * IN_F + lane * 4);
    ushort4 o; o.x = f2bf(v.x); o.y = f2bf(v.y); o.z = f2bf(v.z); o.w = f2bf(v.w);
    *(ushort4*)(Xb + (size_t)node * IN_F + lane * 4) = o;

    float ps[HEADS], pd[HEADS];
#pragma unroll
    for (int hd = 0; hd < HEADS; ++hd) {
        float4 s4 = *(const float4*)(va_s + hd * IN_F + lane * 4);
        float4 d4 = *(const float4*)(va_d + hd * IN_F + lane * 4);
        ps[hd] = v.x * s4.x + v.y * s4.y + v.z * s4.z + v.w * s4.w;
        pd[hd] = v.x * d4.x + v.y * d4.y + v.z * d4.z + v.w * d4.w;
    }
#pragma unroll
    for (int off = 32; off > 0; off >>= 1) {
#pragma unroll
        for (int hd = 0; hd < HEADS; ++hd) {
            ps[hd] += __shfl_xor(ps[hd], off, 64);
            pd[hd] += __shfl_xor(pd[hd], off, 64);
        }
    }
    if (lane == 0) {
        float4 s4 = make_float4(ps[0], ps[1], ps[2], ps[3]);
        float4 d4 = make_float4(pd[0], pd[1], pd[2], pd[3]);
        *(float4*)(a_s + node * 4) = s4;
        *(float4*)(a_d + node * 4) = d4;
    }
}

// --------- fused softmax + X-space aggregation: wave per node ---------
// Gathers go global->LDS directly via global_load_lds with PER-LANE addresses:
// one instruction = 2 edge rows (64 lanes x 16B). Tiles of 8 edges are
// double-buffered in LDS with counted vmcnt(4) waits -- all wave-private, no
// barriers. Consume does packed f32x2 FMAs (v_pk_fma_f32): 8 pk_fma per edge.
// Weights live LDS-duplicated {w,w} so broadcast b128 reads feed pk_fma directly.
#define EDGE(E8)                                                            \
    {                                                                       \
        uint2 u = *(const uint2*)(cons + (E8) * 512);                       \
        float4 wA = *(const float4*)(wp + (E8) * 8);                        \
        float4 wB = *(const float4*)(wp + (E8) * 8 + 4);                    \
        f32x2 f01 = {bflo(u.x), bfhi(u.x)};                                 \
        f32x2 f23 = {bflo(u.y), bfhi(u.y)};                                 \
        f32x2 w0p = {wA.x, wA.y}, w1p = {wA.z, wA.w};                       \
        f32x2 w2p = {wB.x, wB.y}, w3p = {wB.z, wB.w};                       \
        PKFMA(a01[0], f01, w0p); PKFMA(a23[0], f23, w0p);                   \
        PKFMA(a01[1], f01, w1p); PKFMA(a23[1], f23, w1p);                   \
        PKFMA(a01[2], f01, w2p); PKFMA(a23[2], f23, w2p);                   \
        PKFMA(a01[3], f01, w3p); PKFMA(a23[3], f23, w3p);                   \
    }

// issue one 8-edge tile: 4 x global_load_lds, each covering 2 edge rows.
// lgkmcnt(0) first guarantees all prior ds_reads retired before their buffer
// can be overwritten by the new DMA writes.
#define ISSUE(EB, DST)                                                      \
    {                                                                       \
        asm volatile("s_waitcnt lgkmcnt(0)" ::: "memory");                  \
        int s0_ = __shfl(sreg, (EB) + 0, 64);                               \
        int s1_ = __shfl(sreg, (EB) + 1, 64);                               \
        int s2_ = __shfl(sreg, (EB) + 2, 64);                               \
        int s3_ = __shfl(sreg, (EB) + 3, 64);                               \
        int s4_ = __shfl(sreg, (EB) + 4, 64);                               \
        int s5_ = __shfl(sreg, (EB) + 5, 64);                               \
        int s6_ = __shfl(sreg, (EB) + 6, 64);                               \
        int s7_ = __shfl(sreg, (EB) + 7, 64);                               \
        int sa_ = (lane & 32) ? s1_ : s0_;                                  \
        int sb_ = (lane & 32) ? s3_ : s2_;                                  \
        int sc_ = (lane & 32) ? s5_ : s4_;                                  \
        int sd_ = (lane & 32) ? s7_ : s6_;                                  \
        __builtin_amdgcn_global_load_lds((gp_t)(xb16 + (size_t)sa_ * 256),  \
                                         (lp_t)((DST) + 0 * 1024), 16, 0, 0);\
        __builtin_amdgcn_global_load_lds((gp_t)(xb16 + (size_t)sb_ * 256),  \
                                         (lp_t)((DST) + 1 * 1024), 16, 0, 0);\
        __builtin_amdgcn_global_load_lds((gp_t)(xb16 + (size_t)sc_ * 256),  \
                                         (lp_t)((DST) + 2 * 1024), 16, 0, 0);\
        __builtin_amdgcn_global_load_lds((gp_t)(xb16 + (size_t)sd_ * 256),  \
                                         (lp_t)((DST) + 3 * 1024), 16, 0, 0);\
    }

__global__ __launch_bounds__(256) void gat_agg(const ushort* __restrict__ Xb,
                                               const float* __restrict__ a_s,
                                               const float* __restrict__ a_d,
                                               const int* __restrict__ cursor,
                                               const int* __restrict__ table,
                                               ushort* __restrict__ Zb,
                                               int n_nodes) {
    __shared__ ushort xst[4][2][8][256];        // 4 waves x 2 bufs x 8 edges x 512B = 32 KB
    __shared__ f32x2 wse2[4][CAP][4];           // {w,w} per head, per edge       =  8 KB
    const int lane = threadIdx.x & 63;
    const int wid  = threadIdx.x >> 6;
    const int n = blockIdx.x * 4 + wid;
    if (n >= n_nodes) return;                   // no barriers in this kernel
    int deg = cursor[n]; if (deg > CAP) deg = CAP;
    const int* row = table + (size_t)n * CAP;
    const bool act = lane < deg;
    int sreg = act ? row[lane] : n;             // lane e holds src[e] (self if inactive)

    const ushort* xb16 = Xb + (lane & 31) * 8;  // per-lane 16B chunk base
    const uint2* xb2 = (const uint2*)Xb;
    uint2 uself = xb2[(size_t)n * 64 + lane];   // self row (registers)

    const int ntiles = (deg + 7) >> 3;
    if (ntiles > 0) ISSUE(0, (char*)&xst[wid][0][0][0]);   // tile 0 in flight under softmax

    // ---- softmax over self + in-edges (lane e owns edge e) ----
    const float4 ad4 = *(const float4*)(a_d + n * 4);
    const float4 as4 = *(const float4*)(a_s + n * 4);
    const float ad[4] = {ad4.x, ad4.y, ad4.z, ad4.w};
    float aself[4];
    {
        const float asn[4] = {as4.x, as4.y, as4.z, as4.w};
#pragma unroll
        for (int hd = 0; hd < 4; ++hd) {
            float al0 = asn[hd] + ad[hd];
            aself[hd] = al0 > 0.f ? al0 : NEG * al0;
        }
    }
    float al[4];
    {
        float4 av = *(const float4*)(a_s + (size_t)sreg * 4);
        const float as_[4] = {av.x, av.y, av.z, av.w};
#pragma unroll
        for (int hd = 0; hd < 4; ++hd) {
            float a = as_[hd] + ad[hd];
            a = a > 0.f ? a : NEG * a;
            al[hd] = act ? a : -1e30f;
        }
    }
    float m[4];
#pragma unroll
    for (int hd = 0; hd < 4; ++hd) m[hd] = al[hd];
#pragma unroll
    for (int off = 32; off > 0; off >>= 1)
#pragma unroll
        for (int hd = 0; hd < 4; ++hd)
            m[hd] = fmaxf(m[hd], __shfl_xor(m[hd], off, 64));
#pragma unroll
    for (int hd = 0; hd < 4; ++hd) m[hd] = fmaxf(m[hd], aself[hd]);

    float w[4], den[4];
#pragma unroll
    for (int hd = 0; hd < 4; ++hd) {
        w[hd] = act ? __expf(al[hd] - m[hd]) : 0.f;
        den[hd] = w[hd];
    }
#pragma unroll
    for (int off = 32; off > 0; off >>= 1)
#pragma unroll
        for (int hd = 0; hd < 4; ++hd)
            den[hd] += __shfl_xor(den[hd], off, 64);

    float es[4], rdv[4];
#pragma unroll
    for (int hd = 0; hd < 4; ++hd) {
        es[hd] = __expf(aself[hd] - m[hd]);
        rdv[hd] = 1.f / (den[hd] + es[hd]);
    }

    // publish duplicated weights {w,w} (wave-private; DS ops are in-order per wave)
    *(float4*)&wse2[wid][lane][0] = make_float4(w[0], w[0], w[1], w[1]);
    *(float4*)&wse2[wid][lane][2] = make_float4(w[2], w[2], w[3], w[3]);

    // ---- aggregation: lane owns channels 4*lane..+3, all 4 heads, packed f32x2 ----
    f32x2 a01[4], a23[4];
    {
        f32x2 s01 = {bflo(uself.x), bfhi(uself.x)};
        f32x2 s23 = {bflo(uself.y), bfhi(uself.y)};
#pragma unroll
        for (int hd = 0; hd < 4; ++hd) {
            f32x2 eh = {es[hd], es[hd]};
            a01[hd] = s01 * eh;
            a23[hd] = s23 * eh;
        }
    }
#pragma unroll 1
    for (int t = 0; t < ntiles; ++t) {
        if (t + 1 < ntiles) {
            ISSUE((t + 1) * 8, (char*)&xst[wid][(t + 1) & 1][0][0]);
            asm volatile("s_waitcnt vmcnt(4)" ::: "memory");
        } else {
            asm volatile("s_waitcnt vmcnt(0)" ::: "memory");
        }
        const char* cons = (const char*)&xst[wid][t & 1][0][0] + lane * 8;
        const float* wp = (const float*)&wse2[wid][t * 8][0];
        EDGE(0); EDGE(1); EDGE(2); EDGE(3);
        EDGE(4); EDGE(5); EDGE(6); EDGE(7);
    }

    ushort* zr = Zb + (size_t)n * K2;
#pragma unroll
    for (int hd = 0; hd < 4; ++hd) {
        f32x2 r2 = {rdv[hd], rdv[hd]};
        f32x2 z01 = a01[hd] * r2;
        f32x2 z23 = a23[hd] * r2;
        ushort4 z;
        z.x = f2bf(z01.x); z.y = f2bf(z01.y);
        z.z = f2bf(z23.x); z.w = f2bf(z23.y);
        *(ushort4*)(zr + hd * 256 + lane * 4) = z;
    }
}

// ---------------- out = tanh(0.25 * Zb @ WT2^T + bias), bf16 MFMA, K=1024 ----------------
// 2-phase pipeline (T3-minimal): LDS double-buffer, STAGE(t+1) issued BEFORE
// compute(t), counted vmcnt(6) + raw s_barrier -- never a full drain in-loop.
#define GBM 64
#define GBN 128
#define GBK 64

__global__ __launch_bounds__(256) void gemm2(const ushort* __restrict__ Zb,
                                             const ushort* __restrict__ WT2,
                                             const float* __restrict__ bias,
                                             float* __restrict__ out,
                                             int n_nodes) {
    __shared__ ushort As[2][GBM][GBK];          // 16 KB
    __shared__ ushort Bs[2][GBN][GBK];          // 32 KB
    const int tid = threadIdx.x;
    const int m0 = blockIdx.y * GBM;
    const int wave = tid >> 6, lane = tid & 63;
    const int wm = (wave & 1) * 32, wn = (wave >> 1) * 64;
    const int l15 = lane & 15, quad = lane >> 4;

    // staging: per instr a wave covers 8 rows (lane>>3), chunk slot lane&7.
    const int rr8 = lane >> 3;
    const int cg  = (lane & 7) ^ rr8;           // pre-swizzled global chunk
    const ushort* gA0 = Zb + (size_t)(m0 + wave * 16 + rr8) * K2 + cg * 8;
    const ushort* gA1 = gA0 + 8 * K2;
    const ushort* gB0 = WT2 + (size_t)(wave * 32 + rr8) * K2 + cg * 8;
    const ushort* gB1 = gB0 + 8 * K2;
    const ushort* gB2 = gB0 + 16 * K2;
    const ushort* gB3 = gB0 + 24 * K2;

#define STAGE(T, B)                                                          \
    {                                                                        \
        const int ko_ = (T) * GBK;                                           \
        __builtin_amdgcn_global_load_lds((gp_t)(gA0 + ko_),                  \
            (lp_t)&As[B][wave * 16][0], 16, 0, 0);                           \
        __builtin_amdgcn_global_load_lds((gp_t)(gA1 + ko_),                  \
            (lp_t)&As[B][wave * 16 + 8][0], 16, 0, 0);                       \
        __builtin_amdgcn_global_load_lds((gp_t)(gB0 + ko_),                  \
            (lp_t)&Bs[B][wave * 32][0], 16, 0, 0);                           \
        __builtin_amdgcn_global_load_lds((gp_t)(gB1 + ko_),                  \
            (lp_t)&Bs[B][wave * 32 + 8][0], 16, 0, 0);                       \
        __builtin_amdgcn_global_load_lds((gp_t)(gB2 + ko_),                  \
            (lp_t)&Bs[B][wave * 32 + 16][0], 16, 0, 0);                      \
        __builtin_amdgcn_global_load_lds((gp_t)(gB3 + ko_),                  \
            (lp_t)&Bs[B][wave * 32 + 24][0], 16, 0, 0);                      \
    }

    f32x4 acc[2][4];
#pragma unroll
    for (int i = 0; i < 2; ++i)
#pragma unroll
        for (int j = 0; j < 4; ++j) acc[i][j] = (f32x4){0.f, 0.f, 0.f, 0.f};

    const int NT = K2 / GBK;                    // 16
    STAGE(0, 0);
#pragma unroll 1
    for (int t = 0; t < NT; ++t) {
        const int b = t & 1;
        if (t + 1 < NT) {
            STAGE(t + 1, b ^ 1);
            asm volatile("s_waitcnt vmcnt(6)" ::: "memory");
        } else {
            asm volatile("s_waitcnt vmcnt(0)" ::: "memory");
        }
        asm volatile("s_barrier" ::: "memory");     // tile t visible to all waves

#pragma unroll
        for (int tt = 0; tt < 2; ++tt) {
            const int sl = ((tt * 4 + quad) ^ (l15 & 7)) * 8;
            short8 af[2], bf_[4];
#pragma unroll
            for (int fm = 0; fm < 2; ++fm)
                af[fm] = *(const short8*)&As[b][wm + fm * 16 + l15][sl];
#pragma unroll
            for (int fn = 0; fn < 4; ++fn)
                bf_[fn] = *(const short8*)&Bs[b][wn + fn * 16 + l15][sl];
#pragma unroll
            for (int fm = 0; fm < 2; ++fm)
#pragma unroll
                for (int fn = 0; fn < 4; ++fn)
                    acc[fm][fn] = __builtin_amdgcn_mfma_f32_16x16x32_bf16(
                        af[fm], bf_[fn], acc[fm][fn], 0, 0, 0);
        }
        asm volatile("s_barrier" ::: "memory");     // all reads done before overwrite
    }

    float bcol[4];
#pragma unroll
    for (int fn = 0; fn < 4; ++fn) bcol[fn] = bias[wn + fn * 16 + l15];

#pragma unroll
    for (int fm = 0; fm < 2; ++fm) {
        int gmb = m0 + wm + fm * 16 + quad * 4;
#pragma unroll
        for (int reg = 0; reg < 4; ++reg) {
            int gm = gmb + reg;
            if (gm < n_nodes) {
#pragma unroll
                for (int fn = 0; fn < 4; ++fn) {
                    float o = tanhf(0.25f * acc[fm][fn][reg] + bcol[fn]);
                    out[(size_t)gm * OUT_F + wn + fn * 16 + l15] = o;
                }
            }
        }
    }
}

extern "C" void kernel_launch(void* const* d_in, const int* in_sizes, int n_in,
                              void* d_out, int out_size, void* d_ws, size_t ws_size,
                              hipStream_t stream) {
    const float* x       = (const float*)d_in[0];
    const int*   ei      = (const int*)d_in[1];
    const float* W       = (const float*)d_in[2];
    const float* att_src = (const float*)d_in[3];
    const float* att_dst = (const float*)d_in[4];
    const float* bias    = (const float*)d_in[5];
    float* out = (float*)d_out;

    const int n_nodes = in_sizes[0] / IN_F;     // 30000
    const int n_edges = in_sizes[1] / 2;        // 480000
    const int* src = ei;
    const int* dst = ei + n_edges;

    char* ws = (char*)d_ws;
    size_t off = 0;
    auto alloc = [&](size_t bytes) -> void* {
        void* p = ws + off;
        off = (off + bytes + 255) & ~(size_t)255;
        return p;
    };
    ushort* Xb     = (ushort*)alloc((size_t)n_nodes * IN_F * sizeof(ushort));   // 15.4 MB
    ushort* Zb     = (ushort*)alloc((size_t)n_nodes * K2 * sizeof(ushort));     // 61.4 MB
    ushort* WT2    = (ushort*)alloc((size_t)OUT_F * K2 * sizeof(ushort));       // 0.26 MB (also Zb tail-overread pad)
    float*  va_s   = (float*)alloc((size_t)HEADS * IN_F * sizeof(float));
    float*  va_d   = (float*)alloc((size_t)HEADS * IN_F * sizeof(float));
    float*  a_s    = (float*)alloc((size_t)n_nodes * HEADS * sizeof(float));
    float*  a_d    = (float*)alloc((size_t)n_nodes * HEADS * sizeof(float));
    int*    cursor = (int*)alloc((size_t)n_nodes * sizeof(int));
    int*    table  = (int*)alloc((size_t)n_nodes * CAP * sizeof(int));          // 7.7 MB
    (void)ws_size; (void)n_in; (void)out_size;

    hipMemsetAsync(cursor, 0, (size_t)n_nodes * sizeof(int), stream);

    const int nebk = (n_edges + 255) / 256;     // 1875
    prep<<<768 + nebk, 256, 0, stream>>>(W, att_src, att_dst, src, dst,
                                         WT2, va_s, va_d, cursor, table, n_edges);
    fused_x<<<(n_nodes + 3) / 4, 256, 0, stream>>>(x, va_s, va_d, Xb, a_s, a_d, n_nodes);
    gat_agg<<<(n_nodes + 3) / 4, 256, 0, stream>>>(Xb, a_s, a_d, cursor, table,
                                                   Zb, n_nodes);

    dim3 ggrid(1, (n_nodes + GBM - 1) / GBM);   // 1 x 469
    gemm2<<<ggrid, 256, 0, stream>>>(Zb, WT2, bias, out, n_nodes);
}